// Round 25
// baseline (41.849 us; speedup 1.0000x reference)
//
#include <hip/hip_runtime.h>
#include <hip/hip_bf16.h>

// DualMem fast_get_image_pred:
//   logits[b,c] = 100 * (Σ_m w_m sim_m) / sqrt(Σ_{i,j} w_i w_j G[c,i,j])
//
// Lesson ledger (25 rounds):
//  - R21/R22/R23/R24 all ~22.5-22.9us across: fragment-pattern loads,
//    0.5x/2x occupancy, and perfectly-sequential LDS-staged streaming.
//    => the floor is NOT bytes / line-touches / concurrency / DRAM
//    locality. Harness poisons ws ONCE before timing (not between
//    replays) so mem is L3-warm in steady state. Remaining shared
//    structure: 2 serialized dispatches + ~4-deep block tail.
//    Dispatch-count deltas (R19->R21: -13us for -1 dispatch+traffic;
//    R21->R23: +5.5us for +1) suggest ~3-5us/dispatch.
//    THIS round: single dispatch. In-loop img fragment packing is
//    line-budget-neutral vs imgP re-read (64x32 vs 128x16 line-touches),
//    img is L2-resident. Everything else = verified R21 math.
//  - Spill triggers: launch_bounds 2nd arg / non-256 blocks / >=48KB LDS /
//    escaped local arrays.
//  - MFMA C-layout col=lane&15, row=(lane>>4)*4+reg (verified R12/R13).
//
// Structure (1 dispatch):
//   fused2: grid(1000); wave w owns ksteps {8w..8w+7}: packs mem fragment
//     once (mem read once/block), gram rides on packed regs (A==B MFMA),
//     sim vs 4 b-tiles' img fragments packed in-loop. LDS reduce (16.5KB),
//     in-block finish.

constexpr int Bn = 64;     // batch
constexpr int Cn = 1000;   // classes
constexpr int Mn = 11;     // memories per class
constexpr int Dn = 1024;   // feature dim
constexpr float BETA = 5.5f;

typedef __attribute__((ext_vector_type(8))) short bf16x8;
typedef __attribute__((ext_vector_type(4))) float f32x4;

__device__ inline short f2bf(float x) {
    union { __hip_bfloat16 h; short s; } u;
    u.h = __float2bfloat16(x);
    return u.s;
}

__device__ inline bf16x8 pack_bf16x8(const float4 a, const float4 b) {
    bf16x8 r;
    r[0] = f2bf(a.x); r[1] = f2bf(a.y); r[2] = f2bf(a.z); r[3] = f2bf(a.w);
    r[4] = f2bf(b.x); r[5] = f2bf(b.y); r[6] = f2bf(b.z); r[7] = f2bf(b.w);
    return r;
}

__global__ __launch_bounds__(256) void fused2_kernel(
    const float* __restrict__ img, const float* __restrict__ mem,
    float* __restrict__ out) {
    __shared__ float redS[4][Bn][12];   // per-wave partial sims (12 KB)
    __shared__ f32x4 redGp[4][64];      // per-wave gram partials (4 KB)
    __shared__ float redG[Mn * Mn];     // reduced gram (484 B)

    const int c   = blockIdx.x;
    const int tid = threadIdx.x;
    const int l   = tid & 63;
    const int w   = tid >> 6;              // wave owns ksteps {8w..8w+7}
    const int rw  = l & 15;
    const int mrow = (rw < Mn) ? rw : 0;   // pad rows alias row 0
    const int kb   = (l >> 4) * 8;

    const float* mc = mem + (size_t)c * (Mn * Dn) + mrow * Dn + kb;

    f32x4 accS0 = {0.f,0.f,0.f,0.f}, accS1 = {0.f,0.f,0.f,0.f};
    f32x4 accS2 = {0.f,0.f,0.f,0.f}, accS3 = {0.f,0.f,0.f,0.f};
    f32x4 accG  = {0.f,0.f,0.f,0.f};

#pragma unroll
    for (int j = 0; j < 8; ++j) {
        const int kstep = 8 * w + j;
        // pack this kstep's mem fragment ONCE (each mem byte read once/block)
        const float4 m0 = *reinterpret_cast<const float4*>(mc + kstep * 32);
        const float4 m1 = *reinterpret_cast<const float4*>(mc + kstep * 32 + 4);
        const bf16x8 f = pack_bf16x8(m0, m1);
        accG = __builtin_amdgcn_mfma_f32_16x16x32_bf16(f, f, accG, 0, 0, 0);
        // img fragments for the 4 b-tiles, packed in-loop (img is L2-hot)
        const float* ic = img + rw * Dn + kstep * 32 + kb;
        const float4 i00 = *reinterpret_cast<const float4*>(ic);
        const float4 i01 = *reinterpret_cast<const float4*>(ic + 4);
        const float4 i10 = *reinterpret_cast<const float4*>(ic + 16 * Dn);
        const float4 i11 = *reinterpret_cast<const float4*>(ic + 16 * Dn + 4);
        const float4 i20 = *reinterpret_cast<const float4*>(ic + 32 * Dn);
        const float4 i21 = *reinterpret_cast<const float4*>(ic + 32 * Dn + 4);
        const float4 i30 = *reinterpret_cast<const float4*>(ic + 48 * Dn);
        const float4 i31 = *reinterpret_cast<const float4*>(ic + 48 * Dn + 4);
        const bf16x8 a0 = pack_bf16x8(i00, i01);
        const bf16x8 a1 = pack_bf16x8(i10, i11);
        const bf16x8 a2 = pack_bf16x8(i20, i21);
        const bf16x8 a3 = pack_bf16x8(i30, i31);
        accS0 = __builtin_amdgcn_mfma_f32_16x16x32_bf16(a0, f, accS0, 0, 0, 0);
        accS1 = __builtin_amdgcn_mfma_f32_16x16x32_bf16(a1, f, accS1, 0, 0, 0);
        accS2 = __builtin_amdgcn_mfma_f32_16x16x32_bf16(a2, f, accS2, 0, 0, 0);
        accS3 = __builtin_amdgcn_mfma_f32_16x16x32_bf16(a3, f, accS3, 0, 0, 0);
    }

    // stash partials: C layout col=l&15 (m), row=(l>>4)*4+reg (b within tile)
    const int mcol = l & 15;
    const int r0   = (l >> 4) * 4;
    if (mcol < Mn) {
#pragma unroll
        for (int q = 0; q < 4; ++q) {
            redS[w][ 0 + r0 + q][mcol] = accS0[q];
            redS[w][16 + r0 + q][mcol] = accS1[q];
            redS[w][32 + r0 + q][mcol] = accS2[q];
            redS[w][48 + r0 + q][mcol] = accS3[q];
        }
    }
    redGp[w][l] = accG;
    __syncthreads();

    if (tid < 64) {   // wave 0 reduces gram
        const f32x4 g = redGp[0][l] + redGp[1][l] + redGp[2][l] + redGp[3][l];
        if (mcol < Mn) {
            if (r0 + 0 < Mn) redG[(r0 + 0) * Mn + mcol] = g[0];
            if (r0 + 1 < Mn) redG[(r0 + 1) * Mn + mcol] = g[1];
            if (r0 + 2 < Mn) redG[(r0 + 2) * Mn + mcol] = g[2];
            if (r0 + 3 < Mn) redG[(r0 + 3) * Mn + mcol] = g[3];
        }
    }
    __syncthreads();

    // finish: one thread per b
    if (tid < Bn) {
        const int b = tid;
        float wv[Mn];
        float numer = 0.f;
#pragma unroll
        for (int m = 0; m < Mn; ++m) {
            const float s = redS[0][b][m] + redS[1][b][m]
                          + redS[2][b][m] + redS[3][b][m];
            wv[m] = __expf(BETA * (s - 1.f));
            numer = fmaf(wv[m], s, numer);
        }
        float den2 = 0.f;
#pragma unroll
        for (int i = 0; i < Mn; ++i) {
            float row = 0.f;
#pragma unroll
            for (int j = 0; j < Mn; ++j) row = fmaf(wv[j], redG[i * Mn + j], row);
            den2 = fmaf(wv[i], row, den2);
        }
        out[b * Cn + c] = 100.f * numer / sqrtf(den2);
    }
}

extern "C" void kernel_launch(void* const* d_in, const int* in_sizes, int n_in,
                              void* d_out, int out_size, void* d_ws, size_t ws_size,
                              hipStream_t stream) {
    const float* img = (const float*)d_in[0];  // [64][1024] f32
    const float* mem = (const float*)d_in[1];  // [1000][11][1024] f32
    float* out = (float*)d_out;                // [64][1000] f32
    (void)in_sizes; (void)n_in; (void)out_size; (void)d_ws; (void)ws_size;

    fused2_kernel<<<dim3(Cn), dim3(256), 0, stream>>>(img, mem, out);
}

// Round 26
// 28.326 us; speedup vs baseline: 1.4774x; 1.4774x over previous
//
#include <hip/hip_runtime.h>
#include <hip/hip_bf16.h>

// DualMem fast_get_image_pred:
//   logits[b,c] = 100 * (Σ_m w_m sim_m) / sqrt(Σ_{i,j} w_i w_j G[c,i,j])
//
// Lesson ledger (26 rounds):
//  - Line-touch model (recalibrated R25): imgP contiguous fragment loads =
//    16 lines/wave-load; in-loop f32 fragment packing = 32 lines AND 2x the
//    instructions => R25's "dispatch saving" cost +20us. pack_img + imgP is
//    load-bearing. R22 (pack_img + 2-class fused3) = 22.5us champion.
//  - R25 counters (first clean profile of the fused class): FETCH 23MB (mem
//    is L3-WARM in steady state — poison is once, pre-timing), HBM 7%,
//    MfmaUtil 2%, Occupancy 25% (~2 blocks/CU). Aggregate issue-work ~5us
//    => latency-gap-bound at low block residency.
//    THIS round: b-split. Block=(c, b-half): 2 b-tiles, all K, grid(1000,2)
//    (siblings 1000 apart, 1000%8==0 -> same XCD). Gram recomputed per half
//    (rides free on packed fragments); finish in-block; NO partials, NO
//    extra dispatch (R23's confounds). LDS 10.7KB -> ~8 blocks/CU resident.
//  - Spill triggers: launch_bounds 2nd arg / non-256 blocks / >=48KB LDS /
//    escaped local arrays.
//  - MFMA C-layout col=lane&15, row=(lane>>4)*4+reg (verified R12/R13).
//
// Structure (2 dispatches):
//   P1 pack_img: imgP[4][32][64] bf16x8 fragments (128 KB, L2-hot).
//   K1 fused6: grid(1000,2); wave w owns ksteps {8w..8w+7}: packs mem
//      fragment once, gram MFMA (A==B), sim vs 2 b-tiles' imgP. LDS reduce
//      (10.7 KB), in-block finish for 32 b's.
//   Fallback (ws < 128KB): R21-style self-contained fused2 (slower, correct).

constexpr int Bn = 64;     // batch
constexpr int Cn = 1000;   // classes
constexpr int Mn = 11;     // memories per class
constexpr int Dn = 1024;   // feature dim
constexpr float BETA = 5.5f;

typedef __attribute__((ext_vector_type(8))) short bf16x8;
typedef __attribute__((ext_vector_type(4))) float f32x4;

__device__ inline short f2bf(float x) {
    union { __hip_bfloat16 h; short s; } u;
    u.h = __float2bfloat16(x);
    return u.s;
}

__device__ inline bf16x8 pack_bf16x8(const float4 a, const float4 b) {
    bf16x8 r;
    r[0] = f2bf(a.x); r[1] = f2bf(a.y); r[2] = f2bf(a.z); r[3] = f2bf(a.w);
    r[4] = f2bf(b.x); r[5] = f2bf(b.y); r[6] = f2bf(b.z); r[7] = f2bf(b.w);
    return r;
}

// ---------------- P1: imgP fragments (R18-verified) ----------------
__global__ __launch_bounds__(256) void pack_img_kernel(
    const float* __restrict__ img, bf16x8* __restrict__ imgP) {
    const int t = blockIdx.x * 256 + threadIdx.x;   // 8192 chunks
    const int l = t & 63;
    const int kstep = (t >> 6) & 31;
    const int w = t >> 11;
    const int row = w * 16 + (l & 15);
    const int kcol = kstep * 32 + (l >> 4) * 8;
    const float4 a0 = *reinterpret_cast<const float4*>(img + row * Dn + kcol);
    const float4 a1 = *reinterpret_cast<const float4*>(img + row * Dn + kcol + 4);
    imgP[t] = pack_bf16x8(a0, a1);
}

// ---------------- K1: fused, b-split (2 b-tiles per block) ----------------
__global__ __launch_bounds__(256) void fused6_kernel(
    const bf16x8* __restrict__ imgP, const float* __restrict__ mem,
    float* __restrict__ out) {
    __shared__ float redS[4][32][12];   // per-wave partial sims (6 KB)
    __shared__ f32x4 redGp[4][64];      // per-wave gram partials (4 KB)
    __shared__ float redG[Mn * Mn];     // reduced gram (484 B)

    const int c   = blockIdx.x;
    const int bh  = blockIdx.y;            // b-half: tiles {2bh, 2bh+1}
    const int tid = threadIdx.x;
    const int l   = tid & 63;
    const int w   = tid >> 6;              // wave owns ksteps {8w..8w+7}
    const int rw  = l & 15;
    const int mrow = (rw < Mn) ? rw : 0;   // pad rows alias row 0
    const int kb   = (l >> 4) * 8;

    const float* mc = mem + (size_t)c * (Mn * Dn) + mrow * Dn + kb;
    const bf16x8* pA0 = imgP + (size_t)(2 * bh + 0) * 2048 + l;
    const bf16x8* pA1 = imgP + (size_t)(2 * bh + 1) * 2048 + l;

    f32x4 sS0 = {0.f,0.f,0.f,0.f};   // b-tile 2bh
    f32x4 sS1 = {0.f,0.f,0.f,0.f};   // b-tile 2bh+1
    f32x4 gA  = {0.f,0.f,0.f,0.f};   // gram partial

#pragma unroll
    for (int j = 0; j < 8; ++j) {
        const int kstep = 8 * w + j;
        const float4 m0 = *reinterpret_cast<const float4*>(mc + kstep * 32);
        const float4 m1 = *reinterpret_cast<const float4*>(mc + kstep * 32 + 4);
        const bf16x8 f = pack_bf16x8(m0, m1);
        gA = __builtin_amdgcn_mfma_f32_16x16x32_bf16(f, f, gA, 0, 0, 0);
        const bf16x8 a0 = pA0[kstep * 64];
        const bf16x8 a1 = pA1[kstep * 64];
        sS0 = __builtin_amdgcn_mfma_f32_16x16x32_bf16(a0, f, sS0, 0, 0, 0);
        sS1 = __builtin_amdgcn_mfma_f32_16x16x32_bf16(a1, f, sS1, 0, 0, 0);
    }

    // stash partials: C layout col=l&15 (m), row=(l>>4)*4+reg (b within tile)
    const int mcol = l & 15;
    const int r0   = (l >> 4) * 4;
    if (mcol < Mn) {
#pragma unroll
        for (int q = 0; q < 4; ++q) {
            redS[w][ 0 + r0 + q][mcol] = sS0[q];
            redS[w][16 + r0 + q][mcol] = sS1[q];
        }
    }
    redGp[w][l] = gA;
    __syncthreads();

    if (tid < 64) {   // wave 0 reduces gram
        const f32x4 g = redGp[0][l] + redGp[1][l] + redGp[2][l] + redGp[3][l];
        if (mcol < Mn) {
            if (r0 + 0 < Mn) redG[(r0 + 0) * Mn + mcol] = g[0];
            if (r0 + 1 < Mn) redG[(r0 + 1) * Mn + mcol] = g[1];
            if (r0 + 2 < Mn) redG[(r0 + 2) * Mn + mcol] = g[2];
            if (r0 + 3 < Mn) redG[(r0 + 3) * Mn + mcol] = g[3];
        }
    }
    __syncthreads();

    // finish: one thread per b (32 b's in this block)
    if (tid < 32) {
        const int bl = tid;                 // local b (0..31)
        const int b  = bh * 32 + bl;        // global b
        float wv[Mn];
        float numer = 0.f;
#pragma unroll
        for (int m = 0; m < Mn; ++m) {
            const float s = redS[0][bl][m] + redS[1][bl][m]
                          + redS[2][bl][m] + redS[3][bl][m];
            wv[m] = __expf(BETA * (s - 1.f));
            numer = fmaf(wv[m], s, numer);
        }
        float den2 = 0.f;
#pragma unroll
        for (int i = 0; i < Mn; ++i) {
            float row = 0.f;
#pragma unroll
            for (int j = 0; j < Mn; ++j) row = fmaf(wv[j], redG[i * Mn + j], row);
            den2 = fmaf(wv[i], row, den2);
        }
        out[b * Cn + c] = 100.f * numer / sqrtf(den2);
    }
}

// ---------------- fallback: self-contained single-dispatch (correct, slower) ----------------
__global__ __launch_bounds__(256) void fused2_kernel(
    const float* __restrict__ img, const float* __restrict__ mem,
    float* __restrict__ out) {
    __shared__ float redS[4][Bn][12];
    __shared__ f32x4 redGp[4][64];
    __shared__ float redG[Mn * Mn];

    const int c   = blockIdx.x;
    const int tid = threadIdx.x;
    const int l   = tid & 63;
    const int w   = tid >> 6;
    const int rw  = l & 15;
    const int mrow = (rw < Mn) ? rw : 0;
    const int kb   = (l >> 4) * 8;

    const float* mc = mem + (size_t)c * (Mn * Dn) + mrow * Dn + kb;

    f32x4 accS0 = {0.f,0.f,0.f,0.f}, accS1 = {0.f,0.f,0.f,0.f};
    f32x4 accS2 = {0.f,0.f,0.f,0.f}, accS3 = {0.f,0.f,0.f,0.f};
    f32x4 accG  = {0.f,0.f,0.f,0.f};

#pragma unroll
    for (int j = 0; j < 8; ++j) {
        const int kstep = 8 * w + j;
        const float4 m0 = *reinterpret_cast<const float4*>(mc + kstep * 32);
        const float4 m1 = *reinterpret_cast<const float4*>(mc + kstep * 32 + 4);
        const bf16x8 f = pack_bf16x8(m0, m1);
        accG = __builtin_amdgcn_mfma_f32_16x16x32_bf16(f, f, accG, 0, 0, 0);
        const float* ic = img + rw * Dn + kstep * 32 + kb;
        const float4 i00 = *reinterpret_cast<const float4*>(ic);
        const float4 i01 = *reinterpret_cast<const float4*>(ic + 4);
        const float4 i10 = *reinterpret_cast<const float4*>(ic + 16 * Dn);
        const float4 i11 = *reinterpret_cast<const float4*>(ic + 16 * Dn + 4);
        const float4 i20 = *reinterpret_cast<const float4*>(ic + 32 * Dn);
        const float4 i21 = *reinterpret_cast<const float4*>(ic + 32 * Dn + 4);
        const float4 i30 = *reinterpret_cast<const float4*>(ic + 48 * Dn);
        const float4 i31 = *reinterpret_cast<const float4*>(ic + 48 * Dn + 4);
        const bf16x8 a0 = pack_bf16x8(i00, i01);
        const bf16x8 a1 = pack_bf16x8(i10, i11);
        const bf16x8 a2 = pack_bf16x8(i20, i21);
        const bf16x8 a3 = pack_bf16x8(i30, i31);
        accS0 = __builtin_amdgcn_mfma_f32_16x16x32_bf16(a0, f, accS0, 0, 0, 0);
        accS1 = __builtin_amdgcn_mfma_f32_16x16x32_bf16(a1, f, accS1, 0, 0, 0);
        accS2 = __builtin_amdgcn_mfma_f32_16x16x32_bf16(a2, f, accS2, 0, 0, 0);
        accS3 = __builtin_amdgcn_mfma_f32_16x16x32_bf16(a3, f, accS3, 0, 0, 0);
    }

    const int mcol = l & 15;
    const int r0   = (l >> 4) * 4;
    if (mcol < Mn) {
#pragma unroll
        for (int q = 0; q < 4; ++q) {
            redS[w][ 0 + r0 + q][mcol] = accS0[q];
            redS[w][16 + r0 + q][mcol] = accS1[q];
            redS[w][32 + r0 + q][mcol] = accS2[q];
            redS[w][48 + r0 + q][mcol] = accS3[q];
        }
    }
    redGp[w][l] = accG;
    __syncthreads();

    if (tid < 64) {
        const f32x4 g = redGp[0][l] + redGp[1][l] + redGp[2][l] + redGp[3][l];
        if (mcol < Mn) {
            if (r0 + 0 < Mn) redG[(r0 + 0) * Mn + mcol] = g[0];
            if (r0 + 1 < Mn) redG[(r0 + 1) * Mn + mcol] = g[1];
            if (r0 + 2 < Mn) redG[(r0 + 2) * Mn + mcol] = g[2];
            if (r0 + 3 < Mn) redG[(r0 + 3) * Mn + mcol] = g[3];
        }
    }
    __syncthreads();

    if (tid < Bn) {
        const int b = tid;
        float wv[Mn];
        float numer = 0.f;
#pragma unroll
        for (int m = 0; m < Mn; ++m) {
            const float s = redS[0][b][m] + redS[1][b][m]
                          + redS[2][b][m] + redS[3][b][m];
            wv[m] = __expf(BETA * (s - 1.f));
            numer = fmaf(wv[m], s, numer);
        }
        float den2 = 0.f;
#pragma unroll
        for (int i = 0; i < Mn; ++i) {
            float row = 0.f;
#pragma unroll
            for (int j = 0; j < Mn; ++j) row = fmaf(wv[j], redG[i * Mn + j], row);
            den2 = fmaf(wv[i], row, den2);
        }
        out[b * Cn + c] = 100.f * numer / sqrtf(den2);
    }
}

extern "C" void kernel_launch(void* const* d_in, const int* in_sizes, int n_in,
                              void* d_out, int out_size, void* d_ws, size_t ws_size,
                              hipStream_t stream) {
    const float* img = (const float*)d_in[0];  // [64][1024] f32
    const float* mem = (const float*)d_in[1];  // [1000][11][1024] f32
    float* out = (float*)d_out;                // [64][1000] f32
    (void)in_sizes; (void)n_in; (void)out_size;

    constexpr size_t IMGP_B = (size_t)4 * 32 * 64 * 16;   // 128 KB

    if (ws_size >= IMGP_B) {
        bf16x8* imgP = (bf16x8*)d_ws;
        pack_img_kernel<<<dim3(32), dim3(256), 0, stream>>>(img, imgP);
        fused6_kernel<<<dim3(Cn, 2), dim3(256), 0, stream>>>(imgP, mem, out);
    } else {
        fused2_kernel<<<dim3(Cn), dim3(256), 0, stream>>>(img, mem, out);
    }
}

// Round 27
// 28.009 us; speedup vs baseline: 1.4941x; 1.0113x over previous
//
#include <hip/hip_runtime.h>
#include <hip/hip_bf16.h>

// DualMem fast_get_image_pred:
//   logits[b,c] = 100 * (Σ_m w_m sim_m) / sqrt(Σ_{i,j} w_i w_j G[c,i,j])
//
// Lesson ledger (27 rounds):
//  - Floor 22.5-22.9us replicated across 4 structures (R21/R22/R24); every
//    single-lever attack failed: occupancy up (R23,R26: +5.8 — both double
//    mem-or-partials line work), dispatch down (R25: +19, in-loop img
//    packing = 4x line cost), sequential streaming (R24: flat).
//  - Decomposition of R22 (22.5): lines ~8.5us (imgP re-read = biggest
//    term), per-block K-chain latency ~4us, pack+graph gaps ~6-8us.
//    THIS round: 4 classes/block (grid 250) — imgP lines amortize 4x,
//    total line work -30%. Phased epilogue reuses one 12KB redS buffer
//    per class (LDS stays 16.9KB < 48KB cliff). Class-pair-batched mem
//    loads cap live regs ~125 (<128-144 historical grant for small-LDS).
//  - Spill triggers: launch_bounds 2nd arg / non-256 blocks / >=48KB LDS /
//    escaped local arrays. Spill check: WRITE_SIZE must stay ~0.3MB.
//  - MFMA C-layout col=lane&15, row=(lane>>4)*4+reg (verified R12/R13).
//
// Structure (2 dispatches):
//   P1 pack_img: imgP[4][32][64] bf16x8 fragments (128 KB, L2-hot).
//   K1 fused7: grid(250); block owns classes {4bx..4bx+3}; wave w owns
//      ksteps {8w..8w+7}: per kstep load 4 imgP frags (shared) + 4 classes'
//      mem frags (pair-batched), 4 gram + 16 sim MFMAs. Phased epilogue:
//      per class {stash partials, barrier, reduce gram, barrier, finish,
//      barrier} reusing one arena.
//   Fallback (ws < 128KB): R21-style self-contained fused2.

constexpr int Bn = 64;     // batch
constexpr int Cn = 1000;   // classes
constexpr int Mn = 11;     // memories per class
constexpr int Dn = 1024;   // feature dim
constexpr float BETA = 5.5f;

typedef __attribute__((ext_vector_type(8))) short bf16x8;
typedef __attribute__((ext_vector_type(4))) float f32x4;

__device__ inline short f2bf(float x) {
    union { __hip_bfloat16 h; short s; } u;
    u.h = __float2bfloat16(x);
    return u.s;
}

__device__ inline bf16x8 pack_bf16x8(const float4 a, const float4 b) {
    bf16x8 r;
    r[0] = f2bf(a.x); r[1] = f2bf(a.y); r[2] = f2bf(a.z); r[3] = f2bf(a.w);
    r[4] = f2bf(b.x); r[5] = f2bf(b.y); r[6] = f2bf(b.z); r[7] = f2bf(b.w);
    return r;
}

// ---------------- P1: imgP fragments (R18-verified) ----------------
__global__ __launch_bounds__(256) void pack_img_kernel(
    const float* __restrict__ img, bf16x8* __restrict__ imgP) {
    const int t = blockIdx.x * 256 + threadIdx.x;   // 8192 chunks
    const int l = t & 63;
    const int kstep = (t >> 6) & 31;
    const int w = t >> 11;
    const int row = w * 16 + (l & 15);
    const int kcol = kstep * 32 + (l >> 4) * 8;
    const float4 a0 = *reinterpret_cast<const float4*>(img + row * Dn + kcol);
    const float4 a1 = *reinterpret_cast<const float4*>(img + row * Dn + kcol + 4);
    imgP[t] = pack_bf16x8(a0, a1);
}

// ---------------- K1: fused, 4 classes/block ----------------
__global__ __launch_bounds__(256) void fused7_kernel(
    const bf16x8* __restrict__ imgP, const float* __restrict__ mem,
    float* __restrict__ out) {
    __shared__ float redS[4][Bn][12];   // per-wave partial sims, ONE class (12 KB)
    __shared__ f32x4 redGp[4][64];      // per-wave gram partials, ONE class (4 KB)
    __shared__ float redG[Mn * Mn];     // reduced gram (484 B)

    const int c0  = blockIdx.x * 4;        // classes c0..c0+3
    const int tid = threadIdx.x;
    const int l   = tid & 63;
    const int w   = tid >> 6;              // wave owns ksteps {8w..8w+7}
    const int rw  = l & 15;
    const int mrow = (rw < Mn) ? rw : 0;   // pad rows alias row 0
    const int kb   = (l >> 4) * 8;

    const float* mcA = mem + (size_t)(c0 + 0) * (Mn * Dn) + mrow * Dn + kb;
    const float* mcB = mem + (size_t)(c0 + 1) * (Mn * Dn) + mrow * Dn + kb;
    const float* mcC = mem + (size_t)(c0 + 2) * (Mn * Dn) + mrow * Dn + kb;
    const float* mcD = mem + (size_t)(c0 + 3) * (Mn * Dn) + mrow * Dn + kb;

    // 4 classes x 4 b-tiles sim accs + 4 gram accs (all static names)
    f32x4 sA0={0,0,0,0}, sA1={0,0,0,0}, sA2={0,0,0,0}, sA3={0,0,0,0}, gA={0,0,0,0};
    f32x4 sB0={0,0,0,0}, sB1={0,0,0,0}, sB2={0,0,0,0}, sB3={0,0,0,0}, gB={0,0,0,0};
    f32x4 sC0={0,0,0,0}, sC1={0,0,0,0}, sC2={0,0,0,0}, sC3={0,0,0,0}, gC={0,0,0,0};
    f32x4 sD0={0,0,0,0}, sD1={0,0,0,0}, sD2={0,0,0,0}, sD3={0,0,0,0}, gD={0,0,0,0};

#pragma unroll
    for (int j = 0; j < 8; ++j) {
        const int kstep = 8 * w + j;
        // shared A-fragments (the 4x amortization)
        const bf16x8* p = imgP + kstep * 64 + l;
        const bf16x8 a0 = p[0];
        const bf16x8 a1 = p[2048];
        const bf16x8 a2 = p[4096];
        const bf16x8 a3 = p[6144];
        // class pair A,B
        {
            const float4 m0 = *reinterpret_cast<const float4*>(mcA + kstep * 32);
            const float4 m1 = *reinterpret_cast<const float4*>(mcA + kstep * 32 + 4);
            const float4 n0 = *reinterpret_cast<const float4*>(mcB + kstep * 32);
            const float4 n1 = *reinterpret_cast<const float4*>(mcB + kstep * 32 + 4);
            const bf16x8 fA = pack_bf16x8(m0, m1);
            const bf16x8 fB = pack_bf16x8(n0, n1);
            gA = __builtin_amdgcn_mfma_f32_16x16x32_bf16(fA, fA, gA, 0, 0, 0);
            gB = __builtin_amdgcn_mfma_f32_16x16x32_bf16(fB, fB, gB, 0, 0, 0);
            sA0 = __builtin_amdgcn_mfma_f32_16x16x32_bf16(a0, fA, sA0, 0, 0, 0);
            sA1 = __builtin_amdgcn_mfma_f32_16x16x32_bf16(a1, fA, sA1, 0, 0, 0);
            sA2 = __builtin_amdgcn_mfma_f32_16x16x32_bf16(a2, fA, sA2, 0, 0, 0);
            sA3 = __builtin_amdgcn_mfma_f32_16x16x32_bf16(a3, fA, sA3, 0, 0, 0);
            sB0 = __builtin_amdgcn_mfma_f32_16x16x32_bf16(a0, fB, sB0, 0, 0, 0);
            sB1 = __builtin_amdgcn_mfma_f32_16x16x32_bf16(a1, fB, sB1, 0, 0, 0);
            sB2 = __builtin_amdgcn_mfma_f32_16x16x32_bf16(a2, fB, sB2, 0, 0, 0);
            sB3 = __builtin_amdgcn_mfma_f32_16x16x32_bf16(a3, fB, sB3, 0, 0, 0);
        }
        // class pair C,D
        {
            const float4 m0 = *reinterpret_cast<const float4*>(mcC + kstep * 32);
            const float4 m1 = *reinterpret_cast<const float4*>(mcC + kstep * 32 + 4);
            const float4 n0 = *reinterpret_cast<const float4*>(mcD + kstep * 32);
            const float4 n1 = *reinterpret_cast<const float4*>(mcD + kstep * 32 + 4);
            const bf16x8 fC = pack_bf16x8(m0, m1);
            const bf16x8 fD = pack_bf16x8(n0, n1);
            gC = __builtin_amdgcn_mfma_f32_16x16x32_bf16(fC, fC, gC, 0, 0, 0);
            gD = __builtin_amdgcn_mfma_f32_16x16x32_bf16(fD, fD, gD, 0, 0, 0);
            sC0 = __builtin_amdgcn_mfma_f32_16x16x32_bf16(a0, fC, sC0, 0, 0, 0);
            sC1 = __builtin_amdgcn_mfma_f32_16x16x32_bf16(a1, fC, sC1, 0, 0, 0);
            sC2 = __builtin_amdgcn_mfma_f32_16x16x32_bf16(a2, fC, sC2, 0, 0, 0);
            sC3 = __builtin_amdgcn_mfma_f32_16x16x32_bf16(a3, fC, sC3, 0, 0, 0);
            sD0 = __builtin_amdgcn_mfma_f32_16x16x32_bf16(a0, fD, sD0, 0, 0, 0);
            sD1 = __builtin_amdgcn_mfma_f32_16x16x32_bf16(a1, fD, sD1, 0, 0, 0);
            sD2 = __builtin_amdgcn_mfma_f32_16x16x32_bf16(a2, fD, sD2, 0, 0, 0);
            sD3 = __builtin_amdgcn_mfma_f32_16x16x32_bf16(a3, fD, sD3, 0, 0, 0);
        }
    }

    const int mcol = l & 15;
    const int r0   = (l >> 4) * 4;

    // phased epilogue: one class at a time through the shared arena
#define FINISH_CLASS(S0, S1, S2, S3, GACC, CIDX)                                \
    {                                                                            \
        if (mcol < Mn) {                                                         \
            _Pragma("unroll")                                                    \
            for (int q = 0; q < 4; ++q) {                                        \
                redS[w][ 0 + r0 + q][mcol] = S0[q];                              \
                redS[w][16 + r0 + q][mcol] = S1[q];                              \
                redS[w][32 + r0 + q][mcol] = S2[q];                              \
                redS[w][48 + r0 + q][mcol] = S3[q];                              \
            }                                                                    \
        }                                                                        \
        redGp[w][l] = GACC;                                                      \
        __syncthreads();                                                         \
        if (tid < 64) {                                                          \
            const f32x4 g = redGp[0][l] + redGp[1][l] + redGp[2][l] + redGp[3][l]; \
            if (mcol < Mn) {                                                     \
                if (r0 + 0 < Mn) redG[(r0 + 0) * Mn + mcol] = g[0];              \
                if (r0 + 1 < Mn) redG[(r0 + 1) * Mn + mcol] = g[1];              \
                if (r0 + 2 < Mn) redG[(r0 + 2) * Mn + mcol] = g[2];              \
                if (r0 + 3 < Mn) redG[(r0 + 3) * Mn + mcol] = g[3];              \
            }                                                                    \
        }                                                                        \
        __syncthreads();                                                         \
        if (tid < Bn) {                                                          \
            const int b = tid;                                                   \
            float wv[Mn];                                                        \
            float numer = 0.f;                                                   \
            _Pragma("unroll")                                                    \
            for (int m = 0; m < Mn; ++m) {                                       \
                const float s = redS[0][b][m] + redS[1][b][m]                    \
                              + redS[2][b][m] + redS[3][b][m];                   \
                wv[m] = __expf(BETA * (s - 1.f));                                \
                numer = fmaf(wv[m], s, numer);                                   \
            }                                                                    \
            float den2 = 0.f;                                                    \
            _Pragma("unroll")                                                    \
            for (int i = 0; i < Mn; ++i) {                                       \
                float row = 0.f;                                                 \
                _Pragma("unroll")                                                \
                for (int jj = 0; jj < Mn; ++jj)                                  \
                    row = fmaf(wv[jj], redG[i * Mn + jj], row);                  \
                den2 = fmaf(wv[i], row, den2);                                   \
            }                                                                    \
            out[b * Cn + (c0 + CIDX)] = 100.f * numer / sqrtf(den2);             \
        }                                                                        \
        __syncthreads();                                                         \
    }

    FINISH_CLASS(sA0, sA1, sA2, sA3, gA, 0)
    FINISH_CLASS(sB0, sB1, sB2, sB3, gB, 1)
    FINISH_CLASS(sC0, sC1, sC2, sC3, gC, 2)
    FINISH_CLASS(sD0, sD1, sD2, sD3, gD, 3)
#undef FINISH_CLASS
}

// ---------------- fallback: self-contained single-dispatch (correct, slower) ----------------
__global__ __launch_bounds__(256) void fused2_kernel(
    const float* __restrict__ img, const float* __restrict__ mem,
    float* __restrict__ out) {
    __shared__ float redS[4][Bn][12];
    __shared__ f32x4 redGp[4][64];
    __shared__ float redG[Mn * Mn];

    const int c   = blockIdx.x;
    const int tid = threadIdx.x;
    const int l   = tid & 63;
    const int w   = tid >> 6;
    const int rw  = l & 15;
    const int mrow = (rw < Mn) ? rw : 0;
    const int kb   = (l >> 4) * 8;

    const float* mc = mem + (size_t)c * (Mn * Dn) + mrow * Dn + kb;

    f32x4 accS0 = {0.f,0.f,0.f,0.f}, accS1 = {0.f,0.f,0.f,0.f};
    f32x4 accS2 = {0.f,0.f,0.f,0.f}, accS3 = {0.f,0.f,0.f,0.f};
    f32x4 accG  = {0.f,0.f,0.f,0.f};

#pragma unroll
    for (int j = 0; j < 8; ++j) {
        const int kstep = 8 * w + j;
        const float4 m0 = *reinterpret_cast<const float4*>(mc + kstep * 32);
        const float4 m1 = *reinterpret_cast<const float4*>(mc + kstep * 32 + 4);
        const bf16x8 f = pack_bf16x8(m0, m1);
        accG = __builtin_amdgcn_mfma_f32_16x16x32_bf16(f, f, accG, 0, 0, 0);
        const float* ic = img + rw * Dn + kstep * 32 + kb;
        const float4 i00 = *reinterpret_cast<const float4*>(ic);
        const float4 i01 = *reinterpret_cast<const float4*>(ic + 4);
        const float4 i10 = *reinterpret_cast<const float4*>(ic + 16 * Dn);
        const float4 i11 = *reinterpret_cast<const float4*>(ic + 16 * Dn + 4);
        const float4 i20 = *reinterpret_cast<const float4*>(ic + 32 * Dn);
        const float4 i21 = *reinterpret_cast<const float4*>(ic + 32 * Dn + 4);
        const float4 i30 = *reinterpret_cast<const float4*>(ic + 48 * Dn);
        const float4 i31 = *reinterpret_cast<const float4*>(ic + 48 * Dn + 4);
        const bf16x8 a0 = pack_bf16x8(i00, i01);
        const bf16x8 a1 = pack_bf16x8(i10, i11);
        const bf16x8 a2 = pack_bf16x8(i20, i21);
        const bf16x8 a3 = pack_bf16x8(i30, i31);
        accS0 = __builtin_amdgcn_mfma_f32_16x16x32_bf16(a0, f, accS0, 0, 0, 0);
        accS1 = __builtin_amdgcn_mfma_f32_16x16x32_bf16(a1, f, accS1, 0, 0, 0);
        accS2 = __builtin_amdgcn_mfma_f32_16x16x32_bf16(a2, f, accS2, 0, 0, 0);
        accS3 = __builtin_amdgcn_mfma_f32_16x16x32_bf16(a3, f, accS3, 0, 0, 0);
    }

    const int mcol = l & 15;
    const int r0   = (l >> 4) * 4;
    if (mcol < Mn) {
#pragma unroll
        for (int q = 0; q < 4; ++q) {
            redS[w][ 0 + r0 + q][mcol] = accS0[q];
            redS[w][16 + r0 + q][mcol] = accS1[q];
            redS[w][32 + r0 + q][mcol] = accS2[q];
            redS[w][48 + r0 + q][mcol] = accS3[q];
        }
    }
    redGp[w][l] = accG;
    __syncthreads();

    if (tid < 64) {
        const f32x4 g = redGp[0][l] + redGp[1][l] + redGp[2][l] + redGp[3][l];
        if (mcol < Mn) {
            if (r0 + 0 < Mn) redG[(r0 + 0) * Mn + mcol] = g[0];
            if (r0 + 1 < Mn) redG[(r0 + 1) * Mn + mcol] = g[1];
            if (r0 + 2 < Mn) redG[(r0 + 2) * Mn + mcol] = g[2];
            if (r0 + 3 < Mn) redG[(r0 + 3) * Mn + mcol] = g[3];
        }
    }
    __syncthreads();

    if (tid < Bn) {
        const int b = tid;
        float wv[Mn];
        float numer = 0.f;
#pragma unroll
        for (int m = 0; m < Mn; ++m) {
            const float s = redS[0][b][m] + redS[1][b][m]
                          + redS[2][b][m] + redS[3][b][m];
            wv[m] = __expf(BETA * (s - 1.f));
            numer = fmaf(wv[m], s, numer);
        }
        float den2 = 0.f;
#pragma unroll
        for (int i = 0; i < Mn; ++i) {
            float row = 0.f;
#pragma unroll
            for (int j = 0; j < Mn; ++j) row = fmaf(wv[j], redG[i * Mn + j], row);
            den2 = fmaf(wv[i], row, den2);
        }
        out[b * Cn + c] = 100.f * numer / sqrtf(den2);
    }
}

extern "C" void kernel_launch(void* const* d_in, const int* in_sizes, int n_in,
                              void* d_out, int out_size, void* d_ws, size_t ws_size,
                              hipStream_t stream) {
    const float* img = (const float*)d_in[0];  // [64][1024] f32
    const float* mem = (const float*)d_in[1];  // [1000][11][1024] f32
    float* out = (float*)d_out;                // [64][1000] f32
    (void)in_sizes; (void)n_in; (void)out_size;

    constexpr size_t IMGP_B = (size_t)4 * 32 * 64 * 16;   // 128 KB

    if (ws_size >= IMGP_B) {
        bf16x8* imgP = (bf16x8*)d_ws;
        pack_img_kernel<<<dim3(32), dim3(256), 0, stream>>>(img, imgP);
        fused7_kernel<<<dim3(Cn / 4), dim3(256), 0, stream>>>(imgP, mem, out);
    } else {
        fused2_kernel<<<dim3(Cn), dim3(256), 0, stream>>>(img, mem, out);
    }
}

// Round 28
// 22.705 us; speedup vs baseline: 1.8432x; 1.2336x over previous
//
#include <hip/hip_runtime.h>
#include <hip/hip_bf16.h>

// DualMem fast_get_image_pred — CHAMPION (R22 config, 22.49us measured):
//   logits[b,c] = 100 * (Σ_m w_m sim_m) / sqrt(Σ_{i,j} w_i w_j G[c,i,j])
//
// Final lesson ledger (28 rounds):
//  - Grid-size sweep complete: 250->28.0, 500->22.5 (CHAMPION), 1000->22.9,
//    2000->28.3. All single-variable attacks on the 22.5 floor falsified:
//    ILP structures (R12-R16 flat), occupancy +/- (R23/R26/R27 worse),
//    dispatch count (R25 +19us), sequential streaming (R24 flat),
//    class amortization 4x (R27 worse). Floor = co-dominant {line-work,
//    per-block chain latency, launch/tail} at their joint optimum.
//  - Key verified techniques: fragment-ordered bf16 pre-pack (R18: the
//    single biggest lever, contiguous 64x16B wave-loads), K-split across
//    waves with mem read once/block (R21), gram riding on packed register
//    fragments (A==B MFMA, R19), 2-class imgP amortization in registers
//    (R22), in-block LDS reduce + fused finish.
//  - Spill triggers (avoid): launch_bounds 2nd arg / non-256 blocks /
//    >=48KB LDS / escaped local arrays.
//  - MFMA C-layout col=lane&15, row=(lane>>4)*4+reg (verified R12/R13).
//
// Structure (2 dispatches):
//   P1 pack_img: imgP[4][32][64] bf16x8 fragments (128 KB, L2-hot).
//   K1 fused3: grid(500); block handles classes {2bx, 2bx+1}; wave w owns
//      ksteps {8w..8w+7}: packs both classes' mem fragments once, gram
//      partials ride on them, sim partials vs all 4 b-tiles' imgP (shared
//      A-frags). LDS reduce, in-block finish for both classes.
//   Fallback (ws < 128KB): R21-style self-contained fused2.

constexpr int Bn = 64;     // batch
constexpr int Cn = 1000;   // classes
constexpr int Mn = 11;     // memories per class
constexpr int Dn = 1024;   // feature dim
constexpr float BETA = 5.5f;

typedef __attribute__((ext_vector_type(8))) short bf16x8;
typedef __attribute__((ext_vector_type(4))) float f32x4;

__device__ inline short f2bf(float x) {
    union { __hip_bfloat16 h; short s; } u;
    u.h = __float2bfloat16(x);
    return u.s;
}

__device__ inline bf16x8 pack_bf16x8(const float4 a, const float4 b) {
    bf16x8 r;
    r[0] = f2bf(a.x); r[1] = f2bf(a.y); r[2] = f2bf(a.z); r[3] = f2bf(a.w);
    r[4] = f2bf(b.x); r[5] = f2bf(b.y); r[6] = f2bf(b.z); r[7] = f2bf(b.w);
    return r;
}

// ---------------- P1: imgP fragments (R18-verified) ----------------
__global__ __launch_bounds__(256) void pack_img_kernel(
    const float* __restrict__ img, bf16x8* __restrict__ imgP) {
    const int t = blockIdx.x * 256 + threadIdx.x;   // 8192 chunks
    const int l = t & 63;
    const int kstep = (t >> 6) & 31;
    const int w = t >> 11;
    const int row = w * 16 + (l & 15);
    const int kcol = kstep * 32 + (l >> 4) * 8;
    const float4 a0 = *reinterpret_cast<const float4*>(img + row * Dn + kcol);
    const float4 a1 = *reinterpret_cast<const float4*>(img + row * Dn + kcol + 4);
    imgP[t] = pack_bf16x8(a0, a1);
}

// ---------------- K1: fused, 2 classes/block, K split across waves ----------------
__global__ __launch_bounds__(256) void fused3_kernel(
    const bf16x8* __restrict__ imgP, const float* __restrict__ mem,
    float* __restrict__ out) {
    __shared__ float redS[2][4][Bn][12];   // per-class per-wave sims (24 KB)
    __shared__ f32x4 redGp[2][4][64];      // per-class per-wave gram (8 KB)
    __shared__ float redG[2][Mn * Mn];     // reduced gram (968 B)

    const int c0  = blockIdx.x * 2;        // classes c0, c0+1
    const int tid = threadIdx.x;
    const int l   = tid & 63;
    const int w   = tid >> 6;              // wave owns ksteps {8w..8w+7}
    const int rw  = l & 15;
    const int mrow = (rw < Mn) ? rw : 0;   // pad rows alias row 0
    const int kb   = (l >> 4) * 8;

    const float* mcA = mem + (size_t)(c0 + 0) * (Mn * Dn) + mrow * Dn + kb;
    const float* mcB = mem + (size_t)(c0 + 1) * (Mn * Dn) + mrow * Dn + kb;

    // class A accumulators
    f32x4 sA0 = {0.f,0.f,0.f,0.f}, sA1 = {0.f,0.f,0.f,0.f};
    f32x4 sA2 = {0.f,0.f,0.f,0.f}, sA3 = {0.f,0.f,0.f,0.f};
    f32x4 gA  = {0.f,0.f,0.f,0.f};
    // class B accumulators
    f32x4 sB0 = {0.f,0.f,0.f,0.f}, sB1 = {0.f,0.f,0.f,0.f};
    f32x4 sB2 = {0.f,0.f,0.f,0.f}, sB3 = {0.f,0.f,0.f,0.f};
    f32x4 gB  = {0.f,0.f,0.f,0.f};

#pragma unroll
    for (int j = 0; j < 8; ++j) {
        const int kstep = 8 * w + j;
        // pack both classes' mem fragments ONCE (each mem byte read once/block)
        const float4 ma0 = *reinterpret_cast<const float4*>(mcA + kstep * 32);
        const float4 ma1 = *reinterpret_cast<const float4*>(mcA + kstep * 32 + 4);
        const float4 mb0 = *reinterpret_cast<const float4*>(mcB + kstep * 32);
        const float4 mb1 = *reinterpret_cast<const float4*>(mcB + kstep * 32 + 4);
        const bf16x8 fA = pack_bf16x8(ma0, ma1);
        const bf16x8 fB = pack_bf16x8(mb0, mb1);
        gA = __builtin_amdgcn_mfma_f32_16x16x32_bf16(fA, fA, gA, 0, 0, 0);
        gB = __builtin_amdgcn_mfma_f32_16x16x32_bf16(fB, fB, gB, 0, 0, 0);
        // A-fragments shared by both classes (the amortization)
        const bf16x8* p = imgP + kstep * 64 + l;
        const bf16x8 a0 = p[0];
        const bf16x8 a1 = p[2048];
        const bf16x8 a2 = p[4096];
        const bf16x8 a3 = p[6144];
        sA0 = __builtin_amdgcn_mfma_f32_16x16x32_bf16(a0, fA, sA0, 0, 0, 0);
        sA1 = __builtin_amdgcn_mfma_f32_16x16x32_bf16(a1, fA, sA1, 0, 0, 0);
        sA2 = __builtin_amdgcn_mfma_f32_16x16x32_bf16(a2, fA, sA2, 0, 0, 0);
        sA3 = __builtin_amdgcn_mfma_f32_16x16x32_bf16(a3, fA, sA3, 0, 0, 0);
        sB0 = __builtin_amdgcn_mfma_f32_16x16x32_bf16(a0, fB, sB0, 0, 0, 0);
        sB1 = __builtin_amdgcn_mfma_f32_16x16x32_bf16(a1, fB, sB1, 0, 0, 0);
        sB2 = __builtin_amdgcn_mfma_f32_16x16x32_bf16(a2, fB, sB2, 0, 0, 0);
        sB3 = __builtin_amdgcn_mfma_f32_16x16x32_bf16(a3, fB, sB3, 0, 0, 0);
    }

    // stash partials: C layout col=l&15 (m), row=(l>>4)*4+reg (b within tile)
    const int mcol = l & 15;
    const int r0   = (l >> 4) * 4;
    if (mcol < Mn) {
#pragma unroll
        for (int q = 0; q < 4; ++q) {
            redS[0][w][ 0 + r0 + q][mcol] = sA0[q];
            redS[0][w][16 + r0 + q][mcol] = sA1[q];
            redS[0][w][32 + r0 + q][mcol] = sA2[q];
            redS[0][w][48 + r0 + q][mcol] = sA3[q];
            redS[1][w][ 0 + r0 + q][mcol] = sB0[q];
            redS[1][w][16 + r0 + q][mcol] = sB1[q];
            redS[1][w][32 + r0 + q][mcol] = sB2[q];
            redS[1][w][48 + r0 + q][mcol] = sB3[q];
        }
    }
    redGp[0][w][l] = gA;
    redGp[1][w][l] = gB;
    __syncthreads();

    // waves 0,1 reduce gram for class 0,1
    if (tid < 128) {
        const int cc = tid >> 6;       // class index (wave-uniform)
        const f32x4 g = redGp[cc][0][l] + redGp[cc][1][l]
                      + redGp[cc][2][l] + redGp[cc][3][l];
        if (mcol < Mn) {
            if (r0 + 0 < Mn) redG[cc][(r0 + 0) * Mn + mcol] = g[0];
            if (r0 + 1 < Mn) redG[cc][(r0 + 1) * Mn + mcol] = g[1];
            if (r0 + 2 < Mn) redG[cc][(r0 + 2) * Mn + mcol] = g[2];
            if (r0 + 3 < Mn) redG[cc][(r0 + 3) * Mn + mcol] = g[3];
        }
    }
    __syncthreads();

    // finish: threads 0-63 -> class 0, 64-127 -> class 1
    if (tid < 128) {
        const int cc = tid >> 6;
        const int b  = tid & 63;
        const int c  = c0 + cc;
        float wv[Mn];
        float numer = 0.f;
#pragma unroll
        for (int m = 0; m < Mn; ++m) {
            const float s = redS[cc][0][b][m] + redS[cc][1][b][m]
                          + redS[cc][2][b][m] + redS[cc][3][b][m];
            wv[m] = __expf(BETA * (s - 1.f));
            numer = fmaf(wv[m], s, numer);
        }
        float den2 = 0.f;
#pragma unroll
        for (int i = 0; i < Mn; ++i) {
            float row = 0.f;
#pragma unroll
            for (int j = 0; j < Mn; ++j)
                row = fmaf(wv[j], redG[cc][i * Mn + j], row);
            den2 = fmaf(wv[i], row, den2);
        }
        out[b * Cn + c] = 100.f * numer / sqrtf(den2);
    }
}

// ---------------- fallback: R21 single-class fused (no ws needed) ----------------
__global__ __launch_bounds__(256) void fused2_kernel(
    const float* __restrict__ img, const float* __restrict__ mem,
    float* __restrict__ out) {
    __shared__ float redS[4][Bn][12];
    __shared__ f32x4 redGp[4][64];
    __shared__ float redG[Mn * Mn];

    const int c   = blockIdx.x;
    const int tid = threadIdx.x;
    const int l   = tid & 63;
    const int w   = tid >> 6;
    const int rw  = l & 15;
    const int mrow = (rw < Mn) ? rw : 0;
    const int kb   = (l >> 4) * 8;

    const float* mc = mem + (size_t)c * (Mn * Dn) + mrow * Dn + kb;

    f32x4 accS0 = {0.f,0.f,0.f,0.f}, accS1 = {0.f,0.f,0.f,0.f};
    f32x4 accS2 = {0.f,0.f,0.f,0.f}, accS3 = {0.f,0.f,0.f,0.f};
    f32x4 accG  = {0.f,0.f,0.f,0.f};

#pragma unroll
    for (int j = 0; j < 8; ++j) {
        const int kstep = 8 * w + j;
        const float4 m0 = *reinterpret_cast<const float4*>(mc + kstep * 32);
        const float4 m1 = *reinterpret_cast<const float4*>(mc + kstep * 32 + 4);
        const bf16x8 f = pack_bf16x8(m0, m1);
        accG = __builtin_amdgcn_mfma_f32_16x16x32_bf16(f, f, accG, 0, 0, 0);
        const float* ic = img + rw * Dn + kstep * 32 + kb;
        const float4 i00 = *reinterpret_cast<const float4*>(ic);
        const float4 i01 = *reinterpret_cast<const float4*>(ic + 4);
        const float4 i10 = *reinterpret_cast<const float4*>(ic + 16 * Dn);
        const float4 i11 = *reinterpret_cast<const float4*>(ic + 16 * Dn + 4);
        const float4 i20 = *reinterpret_cast<const float4*>(ic + 32 * Dn);
        const float4 i21 = *reinterpret_cast<const float4*>(ic + 32 * Dn + 4);
        const float4 i30 = *reinterpret_cast<const float4*>(ic + 48 * Dn);
        const float4 i31 = *reinterpret_cast<const float4*>(ic + 48 * Dn + 4);
        const bf16x8 a0 = pack_bf16x8(i00, i01);
        const bf16x8 a1 = pack_bf16x8(i10, i11);
        const bf16x8 a2 = pack_bf16x8(i20, i21);
        const bf16x8 a3 = pack_bf16x8(i30, i31);
        accS0 = __builtin_amdgcn_mfma_f32_16x16x32_bf16(a0, f, accS0, 0, 0, 0);
        accS1 = __builtin_amdgcn_mfma_f32_16x16x32_bf16(a1, f, accS1, 0, 0, 0);
        accS2 = __builtin_amdgcn_mfma_f32_16x16x32_bf16(a2, f, accS2, 0, 0, 0);
        accS3 = __builtin_amdgcn_mfma_f32_16x16x32_bf16(a3, f, accS3, 0, 0, 0);
    }

    const int mcol = l & 15;
    const int r0   = (l >> 4) * 4;
    if (mcol < Mn) {
#pragma unroll
        for (int q = 0; q < 4; ++q) {
            redS[w][ 0 + r0 + q][mcol] = accS0[q];
            redS[w][16 + r0 + q][mcol] = accS1[q];
            redS[w][32 + r0 + q][mcol] = accS2[q];
            redS[w][48 + r0 + q][mcol] = accS3[q];
        }
    }
    redGp[w][l] = accG;
    __syncthreads();

    if (tid < 64) {
        const f32x4 g = redGp[0][l] + redGp[1][l] + redGp[2][l] + redGp[3][l];
        if (mcol < Mn) {
            if (r0 + 0 < Mn) redG[(r0 + 0) * Mn + mcol] = g[0];
            if (r0 + 1 < Mn) redG[(r0 + 1) * Mn + mcol] = g[1];
            if (r0 + 2 < Mn) redG[(r0 + 2) * Mn + mcol] = g[2];
            if (r0 + 3 < Mn) redG[(r0 + 3) * Mn + mcol] = g[3];
        }
    }
    __syncthreads();

    if (tid < Bn) {
        const int b = tid;
        float wv[Mn];
        float numer = 0.f;
#pragma unroll
        for (int m = 0; m < Mn; ++m) {
            const float s = redS[0][b][m] + redS[1][b][m]
                          + redS[2][b][m] + redS[3][b][m];
            wv[m] = __expf(BETA * (s - 1.f));
            numer = fmaf(wv[m], s, numer);
        }
        float den2 = 0.f;
#pragma unroll
        for (int i = 0; i < Mn; ++i) {
            float row = 0.f;
#pragma unroll
            for (int j = 0; j < Mn; ++j) row = fmaf(wv[j], redG[i * Mn + j], row);
            den2 = fmaf(wv[i], row, den2);
        }
        out[b * Cn + c] = 100.f * numer / sqrtf(den2);
    }
}

extern "C" void kernel_launch(void* const* d_in, const int* in_sizes, int n_in,
                              void* d_out, int out_size, void* d_ws, size_t ws_size,
                              hipStream_t stream) {
    const float* img = (const float*)d_in[0];  // [64][1024] f32
    const float* mem = (const float*)d_in[1];  // [1000][11][1024] f32
    float* out = (float*)d_out;                // [64][1000] f32
    (void)in_sizes; (void)n_in; (void)out_size;

    constexpr size_t IMGP_B = (size_t)4 * 32 * 64 * 16;   // 128 KB

    if (ws_size >= IMGP_B) {
        bf16x8* imgP = (bf16x8*)d_ws;
        pack_img_kernel<<<dim3(32), dim3(256), 0, stream>>>(img, imgP);
        fused3_kernel<<<dim3(Cn / 2), dim3(256), 0, stream>>>(imgP, mem, out);
    } else {
        fused2_kernel<<<dim3(Cn), dim3(256), 0, stream>>>(img, mem, out);
    }
}